// Round 6
// baseline (244.850 us; speedup 1.0000x reference)
//
#include <hip/hip_runtime.h>
#include <cmath>
#include <cstddef>

namespace {

constexpr int cB = 2, cL = 2048, cS = 2048, cD = 1024, cH = 16, cNS = 8, cNSLOT = 512, cHD = 64;

typedef __attribute__((ext_vector_type(8))) short short8;
typedef __attribute__((ext_vector_type(4))) float f32x4;

#define MFMA16(a, b, c) __builtin_amdgcn_mfma_f32_16x16x32_bf16((a), (b), (c), 0, 0, 0)

__device__ __forceinline__ float sigmoidf_(float x) { return 1.f / (1.f + __expf(-x)); }

__device__ __forceinline__ unsigned short f2bf(float x) {
  union { float f; unsigned u; } c; c.f = x;
  unsigned r = c.u + 0x7FFFu + ((c.u >> 16) & 1u);
  return (unsigned short)(r >> 16);
}
__device__ __forceinline__ float bf2f(unsigned short h) {
  union { unsigned u; float f; } c; c.u = ((unsigned)h) << 16;
  return c.f;
}

// unpack 8 u32 (lo16|hi16 pairs) into two short8 fragments
__device__ __forceinline__ void unpack8(const uint4 a, const uint4 b, short8& p0, short8& p1) {
  const unsigned p[8] = {a.x, a.y, a.z, a.w, b.x, b.y, b.z, b.w};
  union { unsigned u[4]; short8 s; } H, L;
#pragma unroll
  for (int i = 0; i < 4; i++) {
    H.u[i] = __builtin_amdgcn_perm(p[2 * i + 1], p[2 * i], 0x05040100u);
    L.u[i] = __builtin_amdgcn_perm(p[2 * i + 1], p[2 * i], 0x07060302u);
  }
  p0 = H.s;
  p1 = L.s;
}

// async global->LDS 16B per lane. lds ptr must be wave-uniform base; HW writes base + lane*16.
__device__ __forceinline__ void async16(const void* g, void* l) {
  __builtin_amdgcn_global_load_lds((const __attribute__((address_space(1))) void*)g,
                                   (__attribute__((address_space(3))) void*)l, 16, 0, 0);
}

// ---------------- fused prep: wsplit | ln_slots | gatekv | qgate_ln ----------------
// grid 8704 x 256: [0,2048) weight split, [2048,2560) ln_slots, [2560,4608) gatekv,
// [4608,8704) qgate_ln.  Activations (mem, Y) emitted hi-only (2-term GEMMs downstream).
__global__ __launch_bounds__(256) void prep_all_kernel(
    const float* __restrict__ Wq, const float* __restrict__ Wk,
    const float* __restrict__ Wv, const float* __restrict__ Wo,
    unsigned short* __restrict__ Wqh, unsigned short* __restrict__ Wql,
    unsigned short* __restrict__ Wkh, unsigned short* __restrict__ Wkl,
    unsigned short* __restrict__ Wvh, unsigned short* __restrict__ Wvl,
    unsigned short* __restrict__ Woh, unsigned short* __restrict__ Wol,
    const float* __restrict__ E, const float* __restrict__ lnkv_g,
    const float* __restrict__ lnkv_b, unsigned short* __restrict__ mh,
    const float* __restrict__ rhos,
    const float* __restrict__ Wpe, float* __restrict__ gkv,
    const float* __restrict__ xq, const float* __restrict__ Cseq,
    const float* __restrict__ lnq_g, const float* __restrict__ lnq_b,
    unsigned short* __restrict__ Yh) {
  __shared__ float sC[cNS];
  __shared__ float rbuf[8];
  const int bid = blockIdx.x;
  const int tid = threadIdx.x;

  if (bid < 2048) {  // ---- weight split (weights keep hi+lo) ----
    const int wid = bid >> 9;
    const size_t off = ((size_t)(bid & 511) * 256 + tid) * 8;
    const float* src = wid == 0 ? Wq : wid == 1 ? Wk : wid == 2 ? Wv : Wo;
    unsigned short* dh = wid == 0 ? Wqh : wid == 1 ? Wkh : wid == 2 ? Wvh : Woh;
    unsigned short* dl = wid == 0 ? Wql : wid == 1 ? Wkl : wid == 2 ? Wvl : Wol;
    const float4 a = *(const float4*)(src + off);
    const float4 b = *(const float4*)(src + off + 4);
    float v[8] = {a.x, a.y, a.z, a.w, b.x, b.y, b.z, b.w};
    unsigned short h8[8], l8[8];
#pragma unroll
    for (int j = 0; j < 8; j++) {
      h8[j] = f2bf(v[j]);
      l8[j] = f2bf(v[j] - bf2f(h8[j]));
    }
    *(uint4*)(dh + off) = *(uint4*)h8;
    *(uint4*)(dl + off) = *(uint4*)l8;
  } else if (bid < 2560) {  // ---- ln_slots -> bf16 hi ----
    const int row = bid - 2048;
    const int d0 = tid * 4;
    const float4 x = *(const float4*)(E + (size_t)row * cD + d0);
    float s1 = x.x + x.y + x.z + x.w;
    float s2 = x.x * x.x + x.y * x.y + x.z * x.z + x.w * x.w;
#pragma unroll
    for (int o = 32; o > 0; o >>= 1) { s1 += __shfl_xor(s1, o, 64); s2 += __shfl_xor(s2, o, 64); }
    if ((tid & 63) == 0) { rbuf[tid >> 6] = s1; rbuf[4 + (tid >> 6)] = s2; }
    __syncthreads();
    s1 = rbuf[0] + rbuf[1] + rbuf[2] + rbuf[3];
    s2 = rbuf[4] + rbuf[5] + rbuf[6] + rbuf[7];
    const float mean = s1 * (1.f / cD);
    const float var = s2 * (1.f / cD) - mean * mean;
    const float inv = rsqrtf(var + 1e-5f);
    const float4 g = *(const float4*)(lnkv_g + d0);
    const float4 b = *(const float4*)(lnkv_b + d0);
    unsigned short h4[4];
    h4[0] = f2bf((x.x - mean) * inv * g.x + b.x);
    h4[1] = f2bf((x.y - mean) * inv * g.y + b.y);
    h4[2] = f2bf((x.z - mean) * inv * g.z + b.z);
    h4[3] = f2bf((x.w - mean) * inv * g.w + b.w);
    *(uint2*)(mh + (size_t)row * cD + d0) = *(uint2*)h4;
  } else if (bid < 4608) {  // ---- gatekv ----
    const int s = bid - 2560;
    if (tid < cNS) {
      const float age = (float)(cS - 1 - s);
      sC[tid] = __expf(age * __logf(rhos[tid]));
    }
    __syncthreads();
    const int d0 = tid * 4;
    float4 o4;
#pragma unroll
    for (int j = 0; j < 4; j++) {
      const float* wr = Wpe + (size_t)(d0 + j) * cNS;
      float gs = 0.f;
#pragma unroll
      for (int m = 0; m < cNS; m++) gs += sC[m] * wr[m];
      ((float*)&o4)[j] = gs * sigmoidf_(gs);
    }
    *(float4*)(gkv + (size_t)s * cD + d0) = o4;
  } else {  // ---- qgate_ln -> bf16 hi ----
    const int row = bid - 4608;
    if (tid < cNS) sC[tid] = Cseq[(size_t)row * cNS + tid];
    __syncthreads();
    const int d0 = tid * 4;
    const float4 x = *(const float4*)(xq + (size_t)row * cD + d0);
    float y[4];
    float s1 = 0.f, s2 = 0.f;
#pragma unroll
    for (int j = 0; j < 4; j++) {
      const float* wr = Wpe + (size_t)(d0 + j) * cNS;
      float gs = 0.f;
#pragma unroll
      for (int m = 0; m < cNS; m++) gs += sC[m] * wr[m];
      const float val = ((const float*)&x)[j] * gs * sigmoidf_(gs);
      y[j] = val;
      s1 += val;
      s2 += val * val;
    }
#pragma unroll
    for (int o = 32; o > 0; o >>= 1) { s1 += __shfl_xor(s1, o, 64); s2 += __shfl_xor(s2, o, 64); }
    if ((tid & 63) == 0) { rbuf[tid >> 6] = s1; rbuf[4 + (tid >> 6)] = s2; }
    __syncthreads();
    s1 = rbuf[0] + rbuf[1] + rbuf[2] + rbuf[3];
    s2 = rbuf[4] + rbuf[5] + rbuf[6] + rbuf[7];
    const float mean = s1 * (1.f / cD);
    const float var = s2 * (1.f / cD) - mean * mean;
    const float inv = rsqrtf(var + 1e-5f);
    const float4 g = *(const float4*)(lnq_g + d0);
    const float4 b = *(const float4*)(lnq_b + d0);
    unsigned short h4[4];
    h4[0] = f2bf((y[0] - mean) * inv * g.x + b.x);
    h4[1] = f2bf((y[1] - mean) * inv * g.y + b.y);
    h4[2] = f2bf((y[2] - mean) * inv * g.z + b.z);
    h4[3] = f2bf((y[3] - mean) * inv * g.w + b.w);
    *(uint2*)(Yh + (size_t)row * cD + d0) = *(uint2*)h4;
  }
}

// ---------------- shared 2-term GEMM body: C[128x64 tile] = A_hi @ (W_hi+W_lo)^T ----------------
// 256 thr (4 waves 2x2; wave = 64m x 32n), BK=32, double-buffered LDS, async staging.
template <int MODE>
__device__ __forceinline__ void gemm2_body(
    const unsigned short* __restrict__ Ahi,
    const unsigned short* __restrict__ Whi, const unsigned short* __restrict__ Wlo,
    float* __restrict__ Cf, unsigned short* __restrict__ Chi,
    int m0, int n0, int N, int K, float scale,
    unsigned short* sA, unsigned short* sBh, unsigned short* sBl) {
  const int tid = threadIdx.x;
  const int wave = tid >> 6, lane = tid & 63;
  const int quad = lane >> 4, l16 = lane & 15;
  const int wy = wave >> 1, wx = wave & 1;        // wave tile: 64(m) x 32(n)
  const int sg = (lane & 3) ^ ((lane >> 3) & 3);  // permuted global granule

  f32x4 acc[4][2];
#pragma unroll
  for (int i = 0; i < 4; i++)
#pragma unroll
    for (int j = 0; j < 2; j++) acc[i][j] = (f32x4){0.f, 0.f, 0.f, 0.f};

  auto stage = [&](int buf, int k0) {
#pragma unroll
    for (int c = 0; c < 2; c++) {
      const int row = c * 64 + wave * 16 + (lane >> 2);
      const size_t ga = (size_t)(m0 + row) * K + k0 + sg * 8;
      async16(Ahi + ga, sA + buf * 4096 + (c * 64 + wave * 16) * 32);
    }
    const int rowb = wave * 16 + (lane >> 2);
    const size_t gb = (size_t)(n0 + rowb) * K + k0 + sg * 8;
    async16(Whi + gb, sBh + buf * 2048 + wave * 16 * 32);
    async16(Wlo + gb, sBl + buf * 2048 + wave * 16 * 32);
  };

  stage(0, 0);
  __syncthreads();
  const int aswz = (l16 >> 1) & 3;
  int buf = 0;
  for (int k0 = 0; k0 < K; k0 += 32, buf ^= 1) {
    if (k0 + 32 < K) stage(buf ^ 1, k0 + 32);  // drains at iter-end barrier
    short8 bh[2], bl2[2];
#pragma unroll
    for (int tj = 0; tj < 2; tj++) {
      const int br = (wx * 32 + tj * 16 + l16) * 32 + ((quad ^ aswz) * 8);
      bh[tj] = *(const short8*)(sBh + buf * 2048 + br);
      bl2[tj] = *(const short8*)(sBl + buf * 2048 + br);
    }
#pragma unroll
    for (int ti = 0; ti < 4; ti++) {
      const int ar = (wy * 64 + ti * 16 + l16) * 32 + ((quad ^ aswz) * 8);
      const short8 ah = *(const short8*)(sA + buf * 4096 + ar);
#pragma unroll
      for (int tj = 0; tj < 2; tj++) {
        acc[ti][tj] = MFMA16(ah, bh[tj], acc[ti][tj]);
        acc[ti][tj] = MFMA16(ah, bl2[tj], acc[ti][tj]);
      }
    }
    __syncthreads();
  }

#pragma unroll
  for (int ti = 0; ti < 4; ti++)
#pragma unroll
    for (int tj = 0; tj < 2; tj++) {
      const int row = m0 + wy * 64 + ti * 16 + quad * 4;
      const int col = n0 + wx * 32 + tj * 16 + l16;
#pragma unroll
      for (int r = 0; r < 4; r++) {
        const size_t idx = (size_t)(row + r) * N + col;
        if constexpr (MODE == 0) {
          Cf[idx] = acc[ti][tj][r];
        } else {
          Chi[idx] = f2bf(acc[ti][tj][r] * scale);
        }
      }
    }
}

// ---------------- fused KV-proj + Q-proj GEMM dispatch ----------------
// 1D grid 640: [0,128) KV jobs (fp32 out, M=512), [128,640) Q job (bf16-hi out, scaled).
__global__ __launch_bounds__(256, 3) void gemm_qkv_kernel(
    const unsigned short* __restrict__ memhi,
    const unsigned short* __restrict__ Wkhi, const unsigned short* __restrict__ Wklo,
    const unsigned short* __restrict__ Wvhi, const unsigned short* __restrict__ Wvlo,
    float* __restrict__ Ek, float* __restrict__ Ev,
    const unsigned short* __restrict__ Yhi,
    const unsigned short* __restrict__ Wqhi, const unsigned short* __restrict__ Wqlo,
    unsigned short* __restrict__ qhi, float qscale) {
  __shared__ __align__(16) unsigned short sA[2 * 128 * 32];
  __shared__ __align__(16) unsigned short sBh[2 * 64 * 32];
  __shared__ __align__(16) unsigned short sBl[2 * 64 * 32];
  const int bid = blockIdx.x;
  if (bid < 128) {
    const int z = bid >> 6, rem = bid & 63;
    const int m0 = (rem >> 4) * 128, n0 = (rem & 15) * 64;
    gemm2_body<0>(memhi, z ? Wvhi : Wkhi, z ? Wvlo : Wklo, z ? Ev : Ek, nullptr,
                  m0, n0, cD, cD, 1.f, sA, sBh, sBl);
  } else {
    const int lid = bid - 128;
    const int m0 = (lid >> 4) * 128, n0 = (lid & 15) * 64;
    gemm2_body<1>(Yhi, Wqhi, Wqlo, nullptr, qhi, m0, n0, cD, cD, qscale, sA, sBh, sBl);
  }
}

// ---------------- O-projection GEMM ----------------
__global__ __launch_bounds__(256, 3) void gemm_o_kernel(
    const unsigned short* __restrict__ AOhi,
    const unsigned short* __restrict__ Wohi, const unsigned short* __restrict__ Wolo,
    float* __restrict__ out) {
  __shared__ __align__(16) unsigned short sA[2 * 128 * 32];
  __shared__ __align__(16) unsigned short sBh[2 * 64 * 32];
  __shared__ __align__(16) unsigned short sBl[2 * 64 * 32];
  gemm2_body<0>(AOhi, Wohi, Wolo, out, nullptr, blockIdx.y * 128, blockIdx.x * 64,
                cD, cD, 1.f, sA, sBh, sBl);
}

// ---------------- fused prep: K gather (row-major, hi) + Vt gather (transposed, hi) ----------------
// grid 3072 x 256: [0,2048) prep_k, [2048,3072) prep_vt.
__global__ __launch_bounds__(256) void prep_kv_kernel(
    const float* __restrict__ Ek, const float* __restrict__ Ev,
    const float* __restrict__ gkv, const int* __restrict__ xidx,
    unsigned short* __restrict__ Khi, unsigned short* __restrict__ Vthi) {
  __shared__ float tile[64][65];
  const int bid = blockIdx.x;
  const int tid = threadIdx.x;
  if (bid < 2048) {  // ---- prep_k ----
    const int t = bid * 256 + tid;
    const int d0 = (t & 127) * 8;
    const int s = (t >> 7) & (cS - 1);
    const int b = t >> 18;
    const int slot = xidx[b * cS + s];
    const float4 e0 = *(const float4*)(Ek + (size_t)slot * cD + d0);
    const float4 e1 = *(const float4*)(Ek + (size_t)slot * cD + d0 + 4);
    const float4 g0 = *(const float4*)(gkv + (size_t)s * cD + d0);
    const float4 g1 = *(const float4*)(gkv + (size_t)s * cD + d0 + 4);
    float v[8] = {e0.x * g0.x, e0.y * g0.y, e0.z * g0.z, e0.w * g0.w,
                  e1.x * g1.x, e1.y * g1.y, e1.z * g1.z, e1.w * g1.w};
    unsigned short h8[8];
#pragma unroll
    for (int j = 0; j < 8; j++) h8[j] = f2bf(v[j]);
    *(uint4*)(Khi + (size_t)(b * cS + s) * cD + d0) = *(uint4*)h8;
  } else {  // ---- prep_vt ----
    const int local = bid - 2048;
    const int s0 = (local & 31) * 64;
    const int d0 = ((local >> 5) & 15) * 64;
    const int b = local >> 9;
    const int sl = tid >> 4;
    const int dl = (tid & 15) * 4;
#pragma unroll
    for (int it = 0; it < 4; it++) {
      const int s = s0 + sl + it * 16;
      const int slot = xidx[b * cS + s];
      const float4 e = *(const float4*)(Ev + (size_t)slot * cD + d0 + dl);
      const float4 g = *(const float4*)(gkv + (size_t)s * cD + d0 + dl);
      tile[sl + it * 16][dl + 0] = e.x * g.x;
      tile[sl + it * 16][dl + 1] = e.y * g.y;
      tile[sl + it * 16][dl + 2] = e.z * g.z;
      tile[sl + it * 16][dl + 3] = e.w * g.w;
    }
    __syncthreads();
    const int dr = tid >> 3;
    const int sc = (tid & 7) * 8;
#pragma unroll
    for (int it = 0; it < 2; it++) {
      const int d = d0 + dr + it * 32;
      unsigned short h8[8];
#pragma unroll
      for (int j = 0; j < 8; j++) h8[j] = f2bf(tile[sc + j][dr + it * 32]);
      *(uint4*)(Vthi + (size_t)(b * cD + d) * cS + s0 + sc) = *(uint4*)h8;
    }
  }
}

// ---------------- MFMA flash attention v14: DMA-staged double-buffered K/V ----------------
// grid (L/64, H, B) = 1024 blocks, 128 thr = 2 waves, wave owns 32 l-rows (2 bands).
// s-chunk 64. Staging now via global_load_lds (8 async16/wave/chunk) into double-buffered
// K/V: removes 8 reg->LDS b128 writes/wave/chunk from the LDS pipe (measured floor 46us
// of 62us) and halves barriers (one per chunk; its auto vmcnt(0) drain lands the DMA,
// latency hidden under compute — gemm2_body's verified pattern). P buffer unpadded
// [2][16][64] with self-consistent column rotation (col + ((row&7)<<2)) & 63 to fit
// LDS = 40960B exactly -> 4 blocks/CU (grid-matched). Compute math unchanged from v13.
__global__ __launch_bounds__(128, 2) void attn_mfma_kernel(
    const unsigned short* __restrict__ qhi,
    const unsigned short* __restrict__ Khi,
    const unsigned short* __restrict__ Vthi,
    unsigned short* __restrict__ AOhi) {
  __shared__ __align__(16) unsigned short sKh[2][64 * 64];
  __shared__ __align__(16) unsigned short sVh[2][64 * 64];
  __shared__ __align__(16) unsigned int sP32[2][16][64];  // [wave][l-row][rotated s-col]

  const int tid = threadIdx.x;
  const int wave = tid >> 6, lane = tid & 63;
  const int quad = lane >> 4, l16 = lane & 15;
  const int lB = blockIdx.x * 64;
  const int h = blockIdx.y, b = blockIdx.z;

  // Q fragments (A-layout); 0.125*log2e folded upstream
  short8 qh[2][2];
#pragma unroll
  for (int t = 0; t < 2; t++) {
    const size_t base =
        (size_t)(b * cL + lB + wave * 32 + t * 16 + l16) * cD + h * cHD + quad * 8;
    qh[t][0] = *(const short8*)(qhi + base);
    qh[t][1] = *(const short8*)(qhi + base + 32);
  }

  short8 ones;
#pragma unroll
  for (int i = 0; i < 8; i++) ones[i] = (short)0x3F80;  // bf16 1.0

  f32x4 O[2][4], dacc[2];
#pragma unroll
  for (int t = 0; t < 2; t++) {
#pragma unroll
    for (int i = 0; i < 4; i++) O[t][i] = (f32x4){0.f, 0.f, 0.f, 0.f};
    dacc[t] = (f32x4){0.f, 0.f, 0.f, 0.f};
  }

  const int srow8 = lane >> 3;        // row within 8-row staging slab
  const int sg = (lane & 7) ^ srow8;  // permuted global granule (pre-swizzled DMA source)
  const int j0 = wave * 4;

  // global bases for the 4 K-slabs + 4 V-slabs this wave DMA-stages (8 rows each)
  size_t kb[4], vb[4];
#pragma unroll
  for (int i = 0; i < 4; i++) {
    const int r = (j0 + i) * 8 + srow8;
    kb[i] = (size_t)(b * cS + r) * cD + h * cHD + sg * 8;
    vb[i] = (size_t)(b * cD + h * cHD + r) * cS + sg * 8;
  }

  // async DMA staging: LDS dest = wave-uniform slab base (HW adds lane*16B = lane*8 u16,
  // matching the previous explicit layout); global src carries the lane swizzle.
  auto stage = [&](int bf, int sn) {
    const size_t kc = (size_t)sn * cD;
#pragma unroll
    for (int i = 0; i < 4; i++) async16(Khi + kb[i] + kc, &sKh[bf][(j0 + i) * 512]);
#pragma unroll
    for (int i = 0; i < 4; i++) async16(Vthi + vb[i] + sn, &sVh[bf][(j0 + i) * 512]);
  };

  stage(0, 0);
  __syncthreads();  // auto vmcnt(0) drain: chunk 0 landed

  int buf = 0;
  for (int s0 = 0; s0 < cS; s0 += 64) {
    // issue next chunk's DMA into the idle buffer (wrapped last iteration, unused)
    stage(buf ^ 1, (s0 + 64) & (cS - 1));

    // QK^T single-bf16 (exp2 domain): each K-frag read feeds both l-bands
    f32x4 sc[2][4];
#pragma unroll
    for (int t = 0; t < 2; t++)
#pragma unroll
      for (int st = 0; st < 4; st++) sc[t][st] = (f32x4){0.f, 0.f, 0.f, 0.f};
    __builtin_amdgcn_s_setprio(1);
#pragma unroll
    for (int st = 0; st < 4; st++) {
      const int srw = st * 16 + l16;
#pragma unroll
      for (int ks = 0; ks < 2; ks++) {
        const int slot = (ks * 4 + quad) ^ (srw & 7);
        const short8 kfh = *(const short8*)&sKh[buf][srw * 64 + slot * 8];
        sc[0][st] = MFMA16(qh[0][ks], kfh, sc[0][st]);
        sc[1][st] = MFMA16(qh[1][ks], kfh, sc[1][st]);
      }
    }
    __builtin_amdgcn_s_setprio(0);

    // P = exp2(sc); band pair packed via v_cvt_pk_bf16_f32 -> rotated LDS columns
#pragma unroll
    for (int st = 0; st < 4; st++)
#pragma unroll
      for (int r = 0; r < 4; r++) {
        const float e0 = __builtin_amdgcn_exp2f(sc[0][st][r]);
        const float e1 = __builtin_amdgcn_exp2f(sc[1][st][r]);
        unsigned pk;
        asm("v_cvt_pk_bf16_f32 %0, %1, %2" : "=v"(pk) : "v"(e0), "v"(e1));
        const int prow = quad * 4 + r;
        const int pcol = (st * 16 + l16 + ((prow & 7) << 2)) & 63;
        sP32[wave][prow][pcol] = pk;
      }

    // P fragments (A-layout), wave-local (compiler inserts lgkmcnt wait).
    // Same rotation on read row l16; 4-u32 groups are multiples of 4 -> never straddle wrap.
    short8 pf0[2], pf1[2];
    {
      const int rrot = (l16 & 7) << 2;
#pragma unroll
      for (int ss = 0; ss < 2; ss++) {
        const uint4 pa = *(const uint4*)&sP32[wave][l16][(ss * 32 + quad * 8 + rrot) & 63];
        const uint4 pb = *(const uint4*)&sP32[wave][l16][(ss * 32 + quad * 8 + 4 + rrot) & 63];
        unpack8(pa, pb, pf0[ss], pf1[ss]);
      }
    }

    // PV single-bf16: each V-frag read feeds both l-bands
    __builtin_amdgcn_s_setprio(1);
#pragma unroll
    for (int dt = 0; dt < 4; dt++) {
      const int drw = dt * 16 + l16;
#pragma unroll
      for (int ss = 0; ss < 2; ss++) {
        const int slot = (ss * 4 + quad) ^ (drw & 7);
        const short8 vfh = *(const short8*)&sVh[buf][drw * 64 + slot * 8];
        O[0][dt] = MFMA16(pf0[ss], vfh, O[0][dt]);
        O[1][dt] = MFMA16(pf1[ss], vfh, O[1][dt]);
      }
    }
    // denominators via ones-MFMA
    dacc[0] = MFMA16(pf0[0], ones, dacc[0]);
    dacc[0] = MFMA16(pf0[1], ones, dacc[0]);
    dacc[1] = MFMA16(pf1[0], ones, dacc[1]);
    dacc[1] = MFMA16(pf1[1], ones, dacc[1]);
    __builtin_amdgcn_s_setprio(0);

    // one barrier per chunk: drains this chunk's DMA (vmcnt) and fences all waves'
    // LDS reads of buf before it is overwritten next iteration.
    __syncthreads();
    buf ^= 1;
  }

  // epilogue: row = quad*4+r, col = dt*16+l16; dacc col-replicated. AO hi-only.
#pragma unroll
  for (int t = 0; t < 2; t++) {
    float inv[4];
#pragma unroll
    for (int r = 0; r < 4; r++) inv[r] = 1.f / dacc[t][r];
#pragma unroll
    for (int dt = 0; dt < 4; dt++)
#pragma unroll
      for (int r = 0; r < 4; r++) {
        const size_t l = (size_t)(b * cL + lB + wave * 32 + t * 16 + quad * 4 + r);
        AOhi[l * cD + h * cHD + dt * 16 + l16] = f2bf(O[t][dt][r] * inv[r]);
      }
  }
}

}  // namespace

extern "C" void kernel_launch(void* const* d_in, const int* in_sizes, int n_in,
                              void* d_out, int out_size, void* d_ws, size_t ws_size,
                              hipStream_t stream) {
  (void)in_sizes; (void)n_in; (void)out_size; (void)ws_size;
  const float* x_q = (const float*)d_in[0];
  const int* x_idx = (const int*)d_in[1];
  const float* E_slots = (const float*)d_in[2];
  const float* rhos = (const float*)d_in[3];
  const float* C_seq = (const float*)d_in[4];
  const float* Wq = (const float*)d_in[5];
  const float* Wk = (const float*)d_in[6];
  const float* Wv = (const float*)d_in[7];
  const float* Wo = (const float*)d_in[8];
  const float* Wpe = (const float*)d_in[9];
  const float* ln_kv_g = (const float*)d_in[10];
  const float* ln_kv_b = (const float*)d_in[11];
  const float* ln_q_g = (const float*)d_in[12];
  const float* ln_q_b = (const float*)d_in[13];
  float* out = (float*)d_out;

  float* ws = (float*)d_ws;
  unsigned short* memhi = (unsigned short*)(ws + 0);         // 512K ushort
  unsigned short* Wkhi = (unsigned short*)(ws + 262144);     // 1M ushort each
  unsigned short* Wklo = (unsigned short*)(ws + 786432);
  unsigned short* Wvhi = (unsigned short*)(ws + 1310720);
  unsigned short* Wvlo = (unsigned short*)(ws + 1835008);
  float* gkv = ws + 2359296;                                 // 2M floats
  unsigned short* Wqhi = (unsigned short*)(ws + 4456448);
  unsigned short* Wqlo = (unsigned short*)(ws + 4980736);
  unsigned short* Wohi = (unsigned short*)(ws + 5505024);
  unsigned short* Wolo = (unsigned short*)(ws + 6029312);
  float* Ek = ws + 6553600;                                  // 512K floats
  float* Ev = ws + 7077888;
  unsigned short* Yhi = (unsigned short*)(ws + 7602176);     // 4M ushort (B*L*D)
  unsigned short* AOhi = (unsigned short*)(ws + 7602176);    // overlay Y (dead after Q GEMM)
  unsigned short* qhi = (unsigned short*)(ws + 9699328);     // 4M ushort
  unsigned short* Khi = (unsigned short*)(ws + 11796480);    // 4M ushort
  unsigned short* Vthi = (unsigned short*)(ws + 13893632);   // 4M ushort -> extent 64 MB

  constexpr float kQScale = 0.125f * 1.44269504088896340736f;  // 1/sqrt(HD) * log2(e)

  prep_all_kernel<<<8704, 256, 0, stream>>>(
      Wq, Wk, Wv, Wo, Wqhi, Wqlo, Wkhi, Wklo, Wvhi, Wvlo, Wohi, Wolo,
      E_slots, ln_kv_g, ln_kv_b, memhi, rhos, Wpe, gkv,
      x_q, C_seq, ln_q_g, ln_q_b, Yhi);
  gemm_qkv_kernel<<<640, 256, 0, stream>>>(
      memhi, Wkhi, Wklo, Wvhi, Wvlo, Ek, Ev, Yhi, Wqhi, Wqlo, qhi, kQScale);
  prep_kv_kernel<<<3072, 256, 0, stream>>>(Ek, Ev, gkv, x_idx, Khi, Vthi);
  attn_mfma_kernel<<<dim3(cL / 64, cH, cB), 128, 0, stream>>>(qhi, Khi, Vthi, AOhi);
  gemm_o_kernel<<<dim3(16, 32), 256, 0, stream>>>(AOhi, Wohi, Wolo, out);
}

// Round 8
// 240.038 us; speedup vs baseline: 1.0200x; 1.0200x over previous
//
#include <hip/hip_runtime.h>
#include <cmath>
#include <cstddef>

namespace {

constexpr int cB = 2, cL = 2048, cS = 2048, cD = 1024, cH = 16, cNS = 8, cNSLOT = 512, cHD = 64;

typedef __attribute__((ext_vector_type(8))) short short8;
typedef __attribute__((ext_vector_type(4))) float f32x4;

#define MFMA16(a, b, c) __builtin_amdgcn_mfma_f32_16x16x32_bf16((a), (b), (c), 0, 0, 0)

__device__ __forceinline__ float sigmoidf_(float x) { return 1.f / (1.f + __expf(-x)); }

__device__ __forceinline__ unsigned short f2bf(float x) {
  union { float f; unsigned u; } c; c.f = x;
  unsigned r = c.u + 0x7FFFu + ((c.u >> 16) & 1u);
  return (unsigned short)(r >> 16);
}
__device__ __forceinline__ float bf2f(unsigned short h) {
  union { unsigned u; float f; } c; c.u = ((unsigned)h) << 16;
  return c.f;
}

// unpack 8 u32 (lo16|hi16 pairs) into two short8 fragments
__device__ __forceinline__ void unpack8(const uint4 a, const uint4 b, short8& p0, short8& p1) {
  const unsigned p[8] = {a.x, a.y, a.z, a.w, b.x, b.y, b.z, b.w};
  union { unsigned u[4]; short8 s; } H, L;
#pragma unroll
  for (int i = 0; i < 4; i++) {
    H.u[i] = __builtin_amdgcn_perm(p[2 * i + 1], p[2 * i], 0x05040100u);
    L.u[i] = __builtin_amdgcn_perm(p[2 * i + 1], p[2 * i], 0x07060302u);
  }
  p0 = H.s;
  p1 = L.s;
}

// async global->LDS 16B per lane. lds ptr must be wave-uniform base; HW writes base + lane*16.
__device__ __forceinline__ void async16(const void* g, void* l) {
  __builtin_amdgcn_global_load_lds((const __attribute__((address_space(1))) void*)g,
                                   (__attribute__((address_space(3))) void*)l, 16, 0, 0);
}

// ---------------- fused prep: wsplit | ln_slots | gatekv | qgate_ln ----------------
// grid 8704 x 256: [0,2048) weight split, [2048,2560) ln_slots, [2560,4608) gatekv,
// [4608,8704) qgate_ln.  Activations (mem, Y) emitted hi-only (2-term GEMMs downstream).
__global__ __launch_bounds__(256) void prep_all_kernel(
    const float* __restrict__ Wq, const float* __restrict__ Wk,
    const float* __restrict__ Wv, const float* __restrict__ Wo,
    unsigned short* __restrict__ Wqh, unsigned short* __restrict__ Wql,
    unsigned short* __restrict__ Wkh, unsigned short* __restrict__ Wkl,
    unsigned short* __restrict__ Wvh, unsigned short* __restrict__ Wvl,
    unsigned short* __restrict__ Woh, unsigned short* __restrict__ Wol,
    const float* __restrict__ E, const float* __restrict__ lnkv_g,
    const float* __restrict__ lnkv_b, unsigned short* __restrict__ mh,
    const float* __restrict__ rhos,
    const float* __restrict__ Wpe, float* __restrict__ gkv,
    const float* __restrict__ xq, const float* __restrict__ Cseq,
    const float* __restrict__ lnq_g, const float* __restrict__ lnq_b,
    unsigned short* __restrict__ Yh) {
  __shared__ float sC[cNS];
  __shared__ float rbuf[8];
  const int bid = blockIdx.x;
  const int tid = threadIdx.x;

  if (bid < 2048) {  // ---- weight split (weights keep hi+lo) ----
    const int wid = bid >> 9;
    const size_t off = ((size_t)(bid & 511) * 256 + tid) * 8;
    const float* src = wid == 0 ? Wq : wid == 1 ? Wk : wid == 2 ? Wv : Wo;
    unsigned short* dh = wid == 0 ? Wqh : wid == 1 ? Wkh : wid == 2 ? Wvh : Woh;
    unsigned short* dl = wid == 0 ? Wql : wid == 1 ? Wkl : wid == 2 ? Wvl : Wol;
    const float4 a = *(const float4*)(src + off);
    const float4 b = *(const float4*)(src + off + 4);
    float v[8] = {a.x, a.y, a.z, a.w, b.x, b.y, b.z, b.w};
    unsigned short h8[8], l8[8];
#pragma unroll
    for (int j = 0; j < 8; j++) {
      h8[j] = f2bf(v[j]);
      l8[j] = f2bf(v[j] - bf2f(h8[j]));
    }
    *(uint4*)(dh + off) = *(uint4*)h8;
    *(uint4*)(dl + off) = *(uint4*)l8;
  } else if (bid < 2560) {  // ---- ln_slots -> bf16 hi ----
    const int row = bid - 2048;
    const int d0 = tid * 4;
    const float4 x = *(const float4*)(E + (size_t)row * cD + d0);
    float s1 = x.x + x.y + x.z + x.w;
    float s2 = x.x * x.x + x.y * x.y + x.z * x.z + x.w * x.w;
#pragma unroll
    for (int o = 32; o > 0; o >>= 1) { s1 += __shfl_xor(s1, o, 64); s2 += __shfl_xor(s2, o, 64); }
    if ((tid & 63) == 0) { rbuf[tid >> 6] = s1; rbuf[4 + (tid >> 6)] = s2; }
    __syncthreads();
    s1 = rbuf[0] + rbuf[1] + rbuf[2] + rbuf[3];
    s2 = rbuf[4] + rbuf[5] + rbuf[6] + rbuf[7];
    const float mean = s1 * (1.f / cD);
    const float var = s2 * (1.f / cD) - mean * mean;
    const float inv = rsqrtf(var + 1e-5f);
    const float4 g = *(const float4*)(lnkv_g + d0);
    const float4 b = *(const float4*)(lnkv_b + d0);
    unsigned short h4[4];
    h4[0] = f2bf((x.x - mean) * inv * g.x + b.x);
    h4[1] = f2bf((x.y - mean) * inv * g.y + b.y);
    h4[2] = f2bf((x.z - mean) * inv * g.z + b.z);
    h4[3] = f2bf((x.w - mean) * inv * g.w + b.w);
    *(uint2*)(mh + (size_t)row * cD + d0) = *(uint2*)h4;
  } else if (bid < 4608) {  // ---- gatekv ----
    const int s = bid - 2560;
    if (tid < cNS) {
      const float age = (float)(cS - 1 - s);
      sC[tid] = __expf(age * __logf(rhos[tid]));
    }
    __syncthreads();
    const int d0 = tid * 4;
    float4 o4;
#pragma unroll
    for (int j = 0; j < 4; j++) {
      const float* wr = Wpe + (size_t)(d0 + j) * cNS;
      float gs = 0.f;
#pragma unroll
      for (int m = 0; m < cNS; m++) gs += sC[m] * wr[m];
      ((float*)&o4)[j] = gs * sigmoidf_(gs);
    }
    *(float4*)(gkv + (size_t)s * cD + d0) = o4;
  } else {  // ---- qgate_ln -> bf16 hi ----
    const int row = bid - 4608;
    if (tid < cNS) sC[tid] = Cseq[(size_t)row * cNS + tid];
    __syncthreads();
    const int d0 = tid * 4;
    const float4 x = *(const float4*)(xq + (size_t)row * cD + d0);
    float y[4];
    float s1 = 0.f, s2 = 0.f;
#pragma unroll
    for (int j = 0; j < 4; j++) {
      const float* wr = Wpe + (size_t)(d0 + j) * cNS;
      float gs = 0.f;
#pragma unroll
      for (int m = 0; m < cNS; m++) gs += sC[m] * wr[m];
      const float val = ((const float*)&x)[j] * gs * sigmoidf_(gs);
      y[j] = val;
      s1 += val;
      s2 += val * val;
    }
#pragma unroll
    for (int o = 32; o > 0; o >>= 1) { s1 += __shfl_xor(s1, o, 64); s2 += __shfl_xor(s2, o, 64); }
    if ((tid & 63) == 0) { rbuf[tid >> 6] = s1; rbuf[4 + (tid >> 6)] = s2; }
    __syncthreads();
    s1 = rbuf[0] + rbuf[1] + rbuf[2] + rbuf[3];
    s2 = rbuf[4] + rbuf[5] + rbuf[6] + rbuf[7];
    const float mean = s1 * (1.f / cD);
    const float var = s2 * (1.f / cD) - mean * mean;
    const float inv = rsqrtf(var + 1e-5f);
    const float4 g = *(const float4*)(lnq_g + d0);
    const float4 b = *(const float4*)(lnq_b + d0);
    unsigned short h4[4];
    h4[0] = f2bf((y[0] - mean) * inv * g.x + b.x);
    h4[1] = f2bf((y[1] - mean) * inv * g.y + b.y);
    h4[2] = f2bf((y[2] - mean) * inv * g.z + b.z);
    h4[3] = f2bf((y[3] - mean) * inv * g.w + b.w);
    *(uint2*)(Yh + (size_t)row * cD + d0) = *(uint2*)h4;
  }
}

// ---------------- shared 2-term GEMM body: C[128x64 tile] = A_hi @ (W_hi+W_lo)^T ----------------
// 256 thr (4 waves 2x2; wave = 64m x 32n), BK=32, double-buffered LDS, async staging.
template <int MODE>
__device__ __forceinline__ void gemm2_body(
    const unsigned short* __restrict__ Ahi,
    const unsigned short* __restrict__ Whi, const unsigned short* __restrict__ Wlo,
    float* __restrict__ Cf, unsigned short* __restrict__ Chi,
    int m0, int n0, int N, int K, float scale,
    unsigned short* sA, unsigned short* sBh, unsigned short* sBl) {
  const int tid = threadIdx.x;
  const int wave = tid >> 6, lane = tid & 63;
  const int quad = lane >> 4, l16 = lane & 15;
  const int wy = wave >> 1, wx = wave & 1;        // wave tile: 64(m) x 32(n)
  const int sg = (lane & 3) ^ ((lane >> 3) & 3);  // permuted global granule

  f32x4 acc[4][2];
#pragma unroll
  for (int i = 0; i < 4; i++)
#pragma unroll
    for (int j = 0; j < 2; j++) acc[i][j] = (f32x4){0.f, 0.f, 0.f, 0.f};

  auto stage = [&](int buf, int k0) {
#pragma unroll
    for (int c = 0; c < 2; c++) {
      const int row = c * 64 + wave * 16 + (lane >> 2);
      const size_t ga = (size_t)(m0 + row) * K + k0 + sg * 8;
      async16(Ahi + ga, sA + buf * 4096 + (c * 64 + wave * 16) * 32);
    }
    const int rowb = wave * 16 + (lane >> 2);
    const size_t gb = (size_t)(n0 + rowb) * K + k0 + sg * 8;
    async16(Whi + gb, sBh + buf * 2048 + wave * 16 * 32);
    async16(Wlo + gb, sBl + buf * 2048 + wave * 16 * 32);
  };

  stage(0, 0);
  __syncthreads();
  const int aswz = (l16 >> 1) & 3;
  int buf = 0;
  for (int k0 = 0; k0 < K; k0 += 32, buf ^= 1) {
    if (k0 + 32 < K) stage(buf ^ 1, k0 + 32);  // drains at iter-end barrier
    short8 bh[2], bl2[2];
#pragma unroll
    for (int tj = 0; tj < 2; tj++) {
      const int br = (wx * 32 + tj * 16 + l16) * 32 + ((quad ^ aswz) * 8);
      bh[tj] = *(const short8*)(sBh + buf * 2048 + br);
      bl2[tj] = *(const short8*)(sBl + buf * 2048 + br);
    }
#pragma unroll
    for (int ti = 0; ti < 4; ti++) {
      const int ar = (wy * 64 + ti * 16 + l16) * 32 + ((quad ^ aswz) * 8);
      const short8 ah = *(const short8*)(sA + buf * 4096 + ar);
#pragma unroll
      for (int tj = 0; tj < 2; tj++) {
        acc[ti][tj] = MFMA16(ah, bh[tj], acc[ti][tj]);
        acc[ti][tj] = MFMA16(ah, bl2[tj], acc[ti][tj]);
      }
    }
    __syncthreads();
  }

#pragma unroll
  for (int ti = 0; ti < 4; ti++)
#pragma unroll
    for (int tj = 0; tj < 2; tj++) {
      const int row = m0 + wy * 64 + ti * 16 + quad * 4;
      const int col = n0 + wx * 32 + tj * 16 + l16;
#pragma unroll
      for (int r = 0; r < 4; r++) {
        const size_t idx = (size_t)(row + r) * N + col;
        if constexpr (MODE == 0) {
          Cf[idx] = acc[ti][tj][r];
        } else {
          Chi[idx] = f2bf(acc[ti][tj][r] * scale);
        }
      }
    }
}

// ---------------- fused KV-proj + Q-proj GEMM dispatch ----------------
// 1D grid 640: [0,128) KV jobs (fp32 out, M=512), [128,640) Q job (bf16-hi out, scaled).
__global__ __launch_bounds__(256, 3) void gemm_qkv_kernel(
    const unsigned short* __restrict__ memhi,
    const unsigned short* __restrict__ Wkhi, const unsigned short* __restrict__ Wklo,
    const unsigned short* __restrict__ Wvhi, const unsigned short* __restrict__ Wvlo,
    float* __restrict__ Ek, float* __restrict__ Ev,
    const unsigned short* __restrict__ Yhi,
    const unsigned short* __restrict__ Wqhi, const unsigned short* __restrict__ Wqlo,
    unsigned short* __restrict__ qhi, float qscale) {
  __shared__ __align__(16) unsigned short sA[2 * 128 * 32];
  __shared__ __align__(16) unsigned short sBh[2 * 64 * 32];
  __shared__ __align__(16) unsigned short sBl[2 * 64 * 32];
  const int bid = blockIdx.x;
  if (bid < 128) {
    const int z = bid >> 6, rem = bid & 63;
    const int m0 = (rem >> 4) * 128, n0 = (rem & 15) * 64;
    gemm2_body<0>(memhi, z ? Wvhi : Wkhi, z ? Wvlo : Wklo, z ? Ev : Ek, nullptr,
                  m0, n0, cD, cD, 1.f, sA, sBh, sBl);
  } else {
    const int lid = bid - 128;
    const int m0 = (lid >> 4) * 128, n0 = (lid & 15) * 64;
    gemm2_body<1>(Yhi, Wqhi, Wqlo, nullptr, qhi, m0, n0, cD, cD, qscale, sA, sBh, sBl);
  }
}

// ---------------- O-projection GEMM ----------------
__global__ __launch_bounds__(256, 3) void gemm_o_kernel(
    const unsigned short* __restrict__ AOhi,
    const unsigned short* __restrict__ Wohi, const unsigned short* __restrict__ Wolo,
    float* __restrict__ out) {
  __shared__ __align__(16) unsigned short sA[2 * 128 * 32];
  __shared__ __align__(16) unsigned short sBh[2 * 64 * 32];
  __shared__ __align__(16) unsigned short sBl[2 * 64 * 32];
  gemm2_body<0>(AOhi, Wohi, Wolo, out, nullptr, blockIdx.y * 128, blockIdx.x * 64,
                cD, cD, 1.f, sA, sBh, sBl);
}

// ---------------- fused prep: K gather (row-major, hi) + Vt gather (transposed, hi) ----------------
// grid 3072 x 256: [0,2048) prep_k, [2048,3072) prep_vt.
__global__ __launch_bounds__(256) void prep_kv_kernel(
    const float* __restrict__ Ek, const float* __restrict__ Ev,
    const float* __restrict__ gkv, const int* __restrict__ xidx,
    unsigned short* __restrict__ Khi, unsigned short* __restrict__ Vthi) {
  __shared__ float tile[64][65];
  const int bid = blockIdx.x;
  const int tid = threadIdx.x;
  if (bid < 2048) {  // ---- prep_k ----
    const int t = bid * 256 + tid;
    const int d0 = (t & 127) * 8;
    const int s = (t >> 7) & (cS - 1);
    const int b = t >> 18;
    const int slot = xidx[b * cS + s];
    const float4 e0 = *(const float4*)(Ek + (size_t)slot * cD + d0);
    const float4 e1 = *(const float4*)(Ek + (size_t)slot * cD + d0 + 4);
    const float4 g0 = *(const float4*)(gkv + (size_t)s * cD + d0);
    const float4 g1 = *(const float4*)(gkv + (size_t)s * cD + d0 + 4);
    float v[8] = {e0.x * g0.x, e0.y * g0.y, e0.z * g0.z, e0.w * g0.w,
                  e1.x * g1.x, e1.y * g1.y, e1.z * g1.z, e1.w * g1.w};
    unsigned short h8[8];
#pragma unroll
    for (int j = 0; j < 8; j++) h8[j] = f2bf(v[j]);
    *(uint4*)(Khi + (size_t)(b * cS + s) * cD + d0) = *(uint4*)h8;
  } else {  // ---- prep_vt ----
    const int local = bid - 2048;
    const int s0 = (local & 31) * 64;
    const int d0 = ((local >> 5) & 15) * 64;
    const int b = local >> 9;
    const int sl = tid >> 4;
    const int dl = (tid & 15) * 4;
#pragma unroll
    for (int it = 0; it < 4; it++) {
      const int s = s0 + sl + it * 16;
      const int slot = xidx[b * cS + s];
      const float4 e = *(const float4*)(Ev + (size_t)slot * cD + d0 + dl);
      const float4 g = *(const float4*)(gkv + (size_t)s * cD + d0 + dl);
      tile[sl + it * 16][dl + 0] = e.x * g.x;
      tile[sl + it * 16][dl + 1] = e.y * g.y;
      tile[sl + it * 16][dl + 2] = e.z * g.z;
      tile[sl + it * 16][dl + 3] = e.w * g.w;
    }
    __syncthreads();
    const int dr = tid >> 3;
    const int sc = (tid & 7) * 8;
#pragma unroll
    for (int it = 0; it < 2; it++) {
      const int d = d0 + dr + it * 32;
      unsigned short h8[8];
#pragma unroll
      for (int j = 0; j < 8; j++) h8[j] = f2bf(tile[sc + j][dr + it * 32]);
      *(uint4*)(Vthi + (size_t)(b * cD + d) * cS + s0 + sc) = *(uint4*)h8;
    }
  }
}

// ---------------- MFMA flash attention v16: v14 verbatim + XCD-group swizzle ----------------
// 1-D grid 1024 blocks, 128 thr = 2 waves, wave owns 32 l-rows (2 bands), s-chunk 64.
// ONLY change vs v14 (verified, 59.3us): block->(h,b,lB) mapping. Blocks sharing (h,b)
// re-read the same 512KB K/V panel; default dispatch round-robins them over 8 XCDs
// (FETCH 71.7MB vs 16MB unique). Remap so each XCD owns 4 complete (h,b) groups
// (2MB <= 4MB L2): xcd=d&7, jj=d>>3, group=xcd*4+(jj>>5), member=jj&31 (bijective).
// P path / staging / MFMA order are bit-identical to v14 (frozen after 4x ~1e-2
// failures from P-path shape deviations).
__global__ __launch_bounds__(128, 2) void attn_mfma_kernel(
    const unsigned short* __restrict__ qhi,
    const unsigned short* __restrict__ Khi,
    const unsigned short* __restrict__ Vthi,
    unsigned short* __restrict__ AOhi) {
  __shared__ __align__(16) unsigned short sKh[2][64 * 64];
  __shared__ __align__(16) unsigned short sVh[2][64 * 64];
  __shared__ __align__(16) unsigned int sP32[2][16][64];  // [wave][l-row][rotated s-col]

  const int tid = threadIdx.x;
  const int wave = tid >> 6, lane = tid & 63;
  const int quad = lane >> 4, l16 = lane & 15;

  // ---- XCD-group swizzle (T1): the only change vs v14 ----
  const int d = blockIdx.x;
  const int xcd = d & 7, jj = d >> 3;
  const int group = xcd * 4 + (jj >> 5);   // 32 (h,b) groups, 4 per XCD
  const int member = jj & 31;              // L-block within group
  const int h = group & 15, b = group >> 4;
  const int lB = member * 64;

  // Q fragments (A-layout); 0.125*log2e folded upstream
  short8 qh[2][2];
#pragma unroll
  for (int t = 0; t < 2; t++) {
    const size_t base =
        (size_t)(b * cL + lB + wave * 32 + t * 16 + l16) * cD + h * cHD + quad * 8;
    qh[t][0] = *(const short8*)(qhi + base);
    qh[t][1] = *(const short8*)(qhi + base + 32);
  }

  short8 ones;
#pragma unroll
  for (int i = 0; i < 8; i++) ones[i] = (short)0x3F80;  // bf16 1.0

  f32x4 O[2][4], dacc[2];
#pragma unroll
  for (int t = 0; t < 2; t++) {
#pragma unroll
    for (int i = 0; i < 4; i++) O[t][i] = (f32x4){0.f, 0.f, 0.f, 0.f};
    dacc[t] = (f32x4){0.f, 0.f, 0.f, 0.f};
  }

  const int srow8 = lane >> 3;        // row within 8-row staging slab
  const int sg = (lane & 7) ^ srow8;  // permuted global granule (pre-swizzled DMA source)
  const int j0 = wave * 4;

  // global bases for the 4 K-slabs + 4 V-slabs this wave DMA-stages (8 rows each)
  size_t kb[4], vb[4];
#pragma unroll
  for (int i = 0; i < 4; i++) {
    const int r = (j0 + i) * 8 + srow8;
    kb[i] = (size_t)(b * cS + r) * cD + h * cHD + sg * 8;
    vb[i] = (size_t)(b * cD + h * cHD + r) * cS + sg * 8;
  }

  // async DMA staging: LDS dest = wave-uniform slab base (HW adds lane*16B = lane*8 u16);
  // global src carries the lane swizzle.
  auto stage = [&](int bf, int sn) {
    const size_t kc = (size_t)sn * cD;
#pragma unroll
    for (int i = 0; i < 4; i++) async16(Khi + kb[i] + kc, &sKh[bf][(j0 + i) * 512]);
#pragma unroll
    for (int i = 0; i < 4; i++) async16(Vthi + vb[i] + sn, &sVh[bf][(j0 + i) * 512]);
  };

  stage(0, 0);
  __syncthreads();  // auto vmcnt(0) drain: chunk 0 landed

  int buf = 0;
  for (int s0 = 0; s0 < cS; s0 += 64) {
    // issue next chunk's DMA into the idle buffer (wrapped last iteration, unused)
    stage(buf ^ 1, (s0 + 64) & (cS - 1));

    // QK^T single-bf16 (exp2 domain): each K-frag read feeds both l-bands
    f32x4 sc[2][4];
#pragma unroll
    for (int t = 0; t < 2; t++)
#pragma unroll
      for (int st = 0; st < 4; st++) sc[t][st] = (f32x4){0.f, 0.f, 0.f, 0.f};
    __builtin_amdgcn_s_setprio(1);
#pragma unroll
    for (int st = 0; st < 4; st++) {
      const int srw = st * 16 + l16;
#pragma unroll
      for (int ks = 0; ks < 2; ks++) {
        const int slot = (ks * 4 + quad) ^ (srw & 7);
        const short8 kfh = *(const short8*)&sKh[buf][srw * 64 + slot * 8];
        sc[0][st] = MFMA16(qh[0][ks], kfh, sc[0][st]);
        sc[1][st] = MFMA16(qh[1][ks], kfh, sc[1][st]);
      }
    }
    __builtin_amdgcn_s_setprio(0);

    // P = exp2(sc); band pair packed via v_cvt_pk_bf16_f32 -> rotated LDS columns
#pragma unroll
    for (int st = 0; st < 4; st++)
#pragma unroll
      for (int r = 0; r < 4; r++) {
        const float e0 = __builtin_amdgcn_exp2f(sc[0][st][r]);
        const float e1 = __builtin_amdgcn_exp2f(sc[1][st][r]);
        unsigned pk;
        asm("v_cvt_pk_bf16_f32 %0, %1, %2" : "=v"(pk) : "v"(e0), "v"(e1));
        const int prow = quad * 4 + r;
        const int pcol = (st * 16 + l16 + ((prow & 7) << 2)) & 63;
        sP32[wave][prow][pcol] = pk;
      }

    // P fragments (A-layout), wave-local (compiler inserts lgkmcnt wait).
    // Same rotation on read row l16; 4-u32 groups are multiples of 4 -> never straddle wrap.
    short8 pf0[2], pf1[2];
    {
      const int rrot = (l16 & 7) << 2;
#pragma unroll
      for (int ss = 0; ss < 2; ss++) {
        const uint4 pa = *(const uint4*)&sP32[wave][l16][(ss * 32 + quad * 8 + rrot) & 63];
        const uint4 pb = *(const uint4*)&sP32[wave][l16][(ss * 32 + quad * 8 + 4 + rrot) & 63];
        unpack8(pa, pb, pf0[ss], pf1[ss]);
      }
    }

    // PV single-bf16: each V-frag read feeds both l-bands
    __builtin_amdgcn_s_setprio(1);
#pragma unroll
    for (int dt = 0; dt < 4; dt++) {
      const int drw = dt * 16 + l16;
#pragma unroll
      for (int ss = 0; ss < 2; ss++) {
        const int slot = (ss * 4 + quad) ^ (drw & 7);
        const short8 vfh = *(const short8*)&sVh[buf][drw * 64 + slot * 8];
        O[0][dt] = MFMA16(pf0[ss], vfh, O[0][dt]);
        O[1][dt] = MFMA16(pf1[ss], vfh, O[1][dt]);
      }
    }
    // denominators via ones-MFMA
    dacc[0] = MFMA16(pf0[0], ones, dacc[0]);
    dacc[0] = MFMA16(pf0[1], ones, dacc[0]);
    dacc[1] = MFMA16(pf1[0], ones, dacc[1]);
    dacc[1] = MFMA16(pf1[1], ones, dacc[1]);
    __builtin_amdgcn_s_setprio(0);

    // one barrier per chunk: drains this chunk's DMA (vmcnt) and fences all waves'
    // LDS reads of buf before it is overwritten next iteration.
    __syncthreads();
    buf ^= 1;
  }

  // epilogue: row = quad*4+r, col = dt*16+l16; dacc col-replicated. AO hi-only.
#pragma unroll
  for (int t = 0; t < 2; t++) {
    float inv[4];
#pragma unroll
    for (int r = 0; r < 4; r++) inv[r] = 1.f / dacc[t][r];
#pragma unroll
    for (int dt = 0; dt < 4; dt++)
#pragma unroll
      for (int r = 0; r < 4; r++) {
        const size_t l = (size_t)(b * cL + lB + wave * 32 + t * 16 + quad * 4 + r);
        AOhi[l * cD + h * cHD + dt * 16 + l16] = f2bf(O[t][dt][r] * inv[r]);
      }
  }
}

}  // namespace

extern "C" void kernel_launch(void* const* d_in, const int* in_sizes, int n_in,
                              void* d_out, int out_size, void* d_ws, size_t ws_size,
                              hipStream_t stream) {
  (void)in_sizes; (void)n_in; (void)out_size; (void)ws_size;
  const float* x_q = (const float*)d_in[0];
  const int* x_idx = (const int*)d_in[1];
  const float* E_slots = (const float*)d_in[2];
  const float* rhos = (const float*)d_in[3];
  const float* C_seq = (const float*)d_in[4];
  const float* Wq = (const float*)d_in[5];
  const float* Wk = (const float*)d_in[6];
  const float* Wv = (const float*)d_in[7];
  const float* Wo = (const float*)d_in[8];
  const float* Wpe = (const float*)d_in[9];
  const float* ln_kv_g = (const float*)d_in[10];
  const float* ln_kv_b = (const float*)d_in[11];
  const float* ln_q_g = (const float*)d_in[12];
  const float* ln_q_b = (const float*)d_in[13];
  float* out = (float*)d_out;

  float* ws = (float*)d_ws;
  unsigned short* memhi = (unsigned short*)(ws + 0);         // 512K ushort
  unsigned short* Wkhi = (unsigned short*)(ws + 262144);     // 1M ushort each
  unsigned short* Wklo = (unsigned short*)(ws + 786432);
  unsigned short* Wvhi = (unsigned short*)(ws + 1310720);
  unsigned short* Wvlo = (unsigned short*)(ws + 1835008);
  float* gkv = ws + 2359296;                                 // 2M floats
  unsigned short* Wqhi = (unsigned short*)(ws + 4456448);
  unsigned short* Wqlo = (unsigned short*)(ws + 4980736);
  unsigned short* Wohi = (unsigned short*)(ws + 5505024);
  unsigned short* Wolo = (unsigned short*)(ws + 6029312);
  float* Ek = ws + 6553600;                                  // 512K floats
  float* Ev = ws + 7077888;
  unsigned short* Yhi = (unsigned short*)(ws + 7602176);     // 4M ushort (B*L*D)
  unsigned short* AOhi = (unsigned short*)(ws + 7602176);    // overlay Y (dead after Q GEMM)
  unsigned short* qhi = (unsigned short*)(ws + 9699328);     // 4M ushort
  unsigned short* Khi = (unsigned short*)(ws + 11796480);    // 4M ushort
  unsigned short* Vthi = (unsigned short*)(ws + 13893632);   // 4M ushort -> extent 64 MB

  constexpr float kQScale = 0.125f * 1.44269504088896340736f;  // 1/sqrt(HD) * log2(e)

  prep_all_kernel<<<8704, 256, 0, stream>>>(
      Wq, Wk, Wv, Wo, Wqhi, Wqlo, Wkhi, Wklo, Wvhi, Wvlo, Wohi, Wolo,
      E_slots, ln_kv_g, ln_kv_b, memhi, rhos, Wpe, gkv,
      x_q, C_seq, ln_q_g, ln_q_b, Yhi);
  gemm_qkv_kernel<<<640, 256, 0, stream>>>(
      memhi, Wkhi, Wklo, Wvhi, Wvlo, Ek, Ev, Yhi, Wqhi, Wqlo, qhi, kQScale);
  prep_kv_kernel<<<3072, 256, 0, stream>>>(Ek, Ev, gkv, x_idx, Khi, Vthi);
  attn_mfma_kernel<<<1024, 128, 0, stream>>>(qhi, Khi, Vthi, AOhi);
  gemm_o_kernel<<<dim3(16, 32), 256, 0, stream>>>(AOhi, Wohi, Wolo, out);
}